// Round 1
// 268.235 us; speedup vs baseline: 1.0268x; 1.0268x over previous
//
#include <hip/hip_runtime.h>
#include <stdint.h>

typedef __bf16 bf16;
typedef __bf16 bf16x8 __attribute__((ext_vector_type(8)));
typedef __bf16 bf16x4 __attribute__((ext_vector_type(4)));
typedef float  f32x4  __attribute__((ext_vector_type(4)));
typedef short  s16x4  __attribute__((ext_vector_type(4)));
typedef unsigned long long ull;

#define GLOAD16(gptr, lptr)                                                     \
  __builtin_amdgcn_global_load_lds(                                             \
      (const __attribute__((address_space(1))) void*)(gptr),                    \
      (__attribute__((address_space(3))) void*)(lptr), 16, 0, 0)

#define MFMA16(a, b, c) __builtin_amdgcn_mfma_f32_16x16x32_bf16((a), (b), (c), 0, 0, 0)
#define MFMA16K16(a, b, c) __builtin_amdgcn_mfma_f32_16x16x16bf16_1k((a), (b), (c), 0, 0, 0)

static constexpr int B_ = 2, L_ = 2048, NH_ = 16, DH_ = 64;
static constexpr float QSCALE = 0.18033688011112042f;  // 0.125 * log2(e)

// ---------- fused prep: maskbits | fp32->bf16 cvt | weight transpose ----------
__global__ __launch_bounds__(256) void k_prep(const float* __restrict__ q,
                                              const float* __restrict__ k,
                                              const float* __restrict__ v,
                                              const int* __restrict__ mask,
                                              const float* __restrict__ wq,
                                              const float* __restrict__ wk,
                                              const float* __restrict__ wv,
                                              const float* __restrict__ wo,
                                              bf16* __restrict__ X,
                                              bf16* __restrict__ Wt,
                                              ull* __restrict__ mb) {
  __shared__ float t[32][33];
  const int bid = blockIdx.x, tid = threadIdx.x;
  if (bid < 32768) {  // mask int32 -> packed bits
    int tt = bid * 256 + tid;
    ull bal = __ballot(mask[tt] != 0);
    if ((tid & 63) == 0) mb[tt >> 6] = bal;
  } else if (bid < 45056) {  // fp32 -> bf16 x4
    int u = bid - 32768;
    int z = u >> 12, x = u & 4095;
    const float* in = z == 0 ? q : (z == 1 ? k : v);
    bf16* out = X + (size_t)z * 4194304;
    int i = x * 256 + tid;
    const float4 f = ((const float4*)in)[i];
    bf16x4 o = {(bf16)f.x, (bf16)f.y, (bf16)f.z, (bf16)f.w};
    ((bf16x4*)out)[i] = o;
  } else {  // weight fp32 KxN -> bf16 NxK
    int u = bid - 45056;
    int z = u >> 10, rem = u & 1023;
    const float* in = z == 0 ? wq : (z == 1 ? wk : (z == 2 ? wv : wo));
    bf16* out = Wt + (size_t)z * 1048576;
    int bx = (rem & 31) * 32, by = (rem >> 5) * 32;
    int x = tid & 31, y = tid >> 5;
#pragma unroll
    for (int r = 0; r < 4; ++r)
      t[y + r * 8][x] = in[(size_t)(by + y + r * 8) * 1024 + bx + x];
    __syncthreads();
#pragma unroll
    for (int r = 0; r < 4; ++r)
      out[(size_t)(bx + y + r * 8) * 1024 + by + x] = (bf16)t[x][y + r * 8];
  }
}

// ---------- batched 3-proj GEMM: 128x128 tile, BK=32 ----------
// z=0: Q scaled by QSCALE. z=2: V pre-tiled per raw-view head (faithful-bug reshape):
//   h = l>>7, i = (l&127)*16 + (col>>6), d = col&63; Vt[bh][((i>>2)*64 + d)*4 + (i&3)]
__global__ __launch_bounds__(256) void k_gemm3(const bf16* __restrict__ Xb,
                                               const bf16* __restrict__ Wb,
                                               const float* __restrict__ b0,
                                               const float* __restrict__ b1,
                                               const float* __restrict__ b2,
                                               bf16* __restrict__ Ob) {
  const int z = blockIdx.z;
  const bf16* A  = Xb + (size_t)z * 4194304;
  const bf16* Bt = Wb + (size_t)z * 1048576;
  const float* bias = z == 0 ? b0 : (z == 1 ? b1 : b2);
  bf16* C = Ob + (size_t)z * 4194304;
  const int m0 = blockIdx.y * 128, n0 = blockIdx.x * 128;
  __shared__ __align__(16) bf16 As[128 * 32];  // slot(r,c) = r*4 + (c ^ ((r>>1)&3))
  __shared__ __align__(16) bf16 Bs[128 * 32];
  const int tid = threadIdx.x, lane = tid & 63, w = tid >> 6, quad = lane >> 4, l15 = lane & 15;
  const int wm = (w & 1) * 64, wn = (w >> 1) * 64;
  f32x4 acc[4][4] = {};
  for (int kt = 0; kt < 32; ++kt) {
    const int kk = kt * 32;
#pragma unroll
    for (int i = 0; i < 2; ++i) {
      int s = tid + i * 256;
      int r = s >> 2, c = (s & 3) ^ ((r >> 1) & 3);
      GLOAD16(A + (size_t)(m0 + r) * 1024 + kk + c * 8, As + s * 8);
      GLOAD16(Bt + (size_t)(n0 + r) * 1024 + kk + c * 8, Bs + s * 8);
    }
    __syncthreads();
    bf16x8 af[4], bb[4];
#pragma unroll
    for (int i = 0; i < 4; ++i) {
      int ra = wm + i * 16 + l15, rb = wn + i * 16 + l15;
      af[i] = *(const bf16x8*)(As + (ra * 4 + (quad ^ ((ra >> 1) & 3))) * 8);
      bb[i] = *(const bf16x8*)(Bs + (rb * 4 + (quad ^ ((rb >> 1) & 3))) * 8);
    }
#pragma unroll
    for (int mi = 0; mi < 4; ++mi)
#pragma unroll
      for (int ni = 0; ni < 4; ++ni)
        acc[mi][ni] = MFMA16(af[mi], bb[ni], acc[mi][ni]);
    __syncthreads();
  }
  const float scale = (z == 0) ? QSCALE : 1.0f;
#pragma unroll
  for (int mi = 0; mi < 4; ++mi)
#pragma unroll
    for (int ni = 0; ni < 4; ++ni) {
      int row = m0 + wm + mi * 16 + quad * 4;
      int col = n0 + wn + ni * 16 + l15;
      float bz = bias[col];
      if (z == 2) {
        int b_ = row >> 11, l = row & 2047;
        int hh = l >> 7;
        int i0 = (l & 127) * 16 + (col >> 6);
        int d  = col & 63;
        bf16* dst = C + (size_t)(b_ * 16 + hh) * 131072;
#pragma unroll
        for (int r = 0; r < 4; ++r) {
          int iK = i0 + 16 * r;
          dst[((size_t)(iK >> 2) * 64 + d) * 4 + (iK & 3)] = (bf16)(acc[mi][ni][r] + bz);
        }
      } else {
#pragma unroll
        for (int r = 0; r < 4; ++r)
          C[(size_t)(row + r) * 1024 + col] = (bf16)((acc[mi][ni][r] + bz) * scale);
      }
    }
}

// ---------- output GEMM: 64x128 tile, fp32 out + bias ----------
__global__ __launch_bounds__(256) void k_gemmo(const bf16* __restrict__ A,
                                               const bf16* __restrict__ Bt,
                                               const float* __restrict__ bias,
                                               float* __restrict__ C) {
  const int m0 = blockIdx.y * 64, n0 = blockIdx.x * 128;
  __shared__ __align__(16) bf16 As[64 * 32];
  __shared__ __align__(16) bf16 Bs[128 * 32];
  const int tid = threadIdx.x, lane = tid & 63, w = tid >> 6, quad = lane >> 4, l15 = lane & 15;
  const int wn = w * 32;
  f32x4 acc[4][2] = {};
  for (int kt = 0; kt < 32; ++kt) {
    const int kk = kt * 32;
    {
      int r = tid >> 2, c = (tid & 3) ^ ((r >> 1) & 3);
      GLOAD16(A + (size_t)(m0 + r) * 1024 + kk + c * 8, As + tid * 8);
    }
#pragma unroll
    for (int i = 0; i < 2; ++i) {
      int s = tid + i * 256;
      int r = s >> 2, c = (s & 3) ^ ((r >> 1) & 3);
      GLOAD16(Bt + (size_t)(n0 + r) * 1024 + kk + c * 8, Bs + s * 8);
    }
    __syncthreads();
    bf16x8 af[4], bb[2];
#pragma unroll
    for (int i = 0; i < 4; ++i) {
      int ra = i * 16 + l15;
      af[i] = *(const bf16x8*)(As + (ra * 4 + (quad ^ ((ra >> 1) & 3))) * 8);
    }
#pragma unroll
    for (int i = 0; i < 2; ++i) {
      int rb = wn + i * 16 + l15;
      bb[i] = *(const bf16x8*)(Bs + (rb * 4 + (quad ^ ((rb >> 1) & 3))) * 8);
    }
#pragma unroll
    for (int mi = 0; mi < 4; ++mi)
#pragma unroll
      for (int ni = 0; ni < 2; ++ni)
        acc[mi][ni] = MFMA16(af[mi], bb[ni], acc[mi][ni]);
    __syncthreads();
  }
#pragma unroll
  for (int mi = 0; mi < 4; ++mi)
#pragma unroll
    for (int ni = 0; ni < 2; ++ni) {
      int row = m0 + mi * 16 + quad * 4;
      int col = n0 + wn + ni * 16 + l15;
      float bz = bias[col];
#pragma unroll
      for (int r = 0; r < 4; ++r)
        C[(size_t)(row + r) * 1024 + col] = acc[mi][ni][r] + bz;
    }
}

// ---------- flash attention: q-tile 128, 512 threads (8 waves, 16 q-rows/wave);
// K+V+mask LDS dbuf, transposed-scores, P in registers, lsum via ones-MFMA ----------
// Grid 512 blocks = 2 blocks/CU; 8 waves/block -> 16 waves/CU (was 8) to fix
// the occupancy-bound latency stall (Occupancy 17.6%, MfmaUtil 32%, VALU 52%).
__global__ __launch_bounds__(512) void k_flash(const bf16* __restrict__ Qp,
                                               const bf16* __restrict__ Kp,
                                               const bf16* __restrict__ Vtp,
                                               const ull* __restrict__ mb,
                                               bf16* __restrict__ ctx) {
  const int b = blockIdx.z, h = blockIdx.y, q0 = blockIdx.x * 128;
  const size_t HEAD = 131072;
  const bf16* Q  = Qp  + ((size_t)b * NH_ + h) * HEAD;  // pre-scaled by QSCALE
  const bf16* K  = Kp  + ((size_t)b * NH_ + h) * HEAD;  // row-major [key][d]
  const bf16* Vt = Vtp + ((size_t)b * NH_ + h) * HEAD;  // pre-tiled [i>>2][d][i&3]
  const ull* mrow = mb + (size_t)b * L_ * 32;

  __shared__ __align__(16) bf16 Ks[2][64 * 64];  // slot(key,c) = key*8 + (c ^ (key&7))
  __shared__ __align__(16) bf16 Vs[2][64 * 64];  // straight copy of pre-tiled chunk
  __shared__ __align__(16) ull  Ms[2][256];      // [buf][row*2 + parity]

  const int tid = threadIdx.x, lane = tid & 63, w = tid >> 6, quad = lane >> 4, l15 = lane & 15;

  // Q fragments (B-operand: n=q=l15, k=ks*32+quad*8+j); wave w owns q rows [w*16, w*16+16)
  bf16x8 qf[2];
#pragma unroll
  for (int ks = 0; ks < 2; ++ks)
    qf[ks] = *(const bf16x8*)(Q + (size_t)(q0 + w * 16 + l15) * 64 + ks * 32 + quad * 8);

  // initial staging: kt=0 K/V (512 threads x 1 slot of 16B), mask word pair (0,1)
  {
    int s = tid;
    int key = s >> 3, c = (s & 7) ^ (key & 7);
    GLOAD16(K + (size_t)key * 64 + c * 8, Ks[0] + s * 8);
    GLOAD16(Vt + (size_t)s * 8, Vs[0] + s * 8);
  }
  if (w < 2) {
    int r = w * 64 + lane;
    GLOAD16(mrow + (size_t)(q0 + r) * 32, (bf16*)&Ms[0][0] + r * 8);
  }
  __syncthreads();

  f32x4 accO[4] = {};
  f32x4 accL = {};
  const s16x4 onesf = {0x3F80, 0x3F80, 0x3F80, 0x3F80};  // bf16 1.0 x4

  for (int kt = 0; kt < 32; ++kt) {
    const int cur = kt & 1;
    // prefetch next K/V (+mask every other kt) into the other LDS buffer
    if (kt + 1 < 32) {
      const int nxt = cur ^ 1;
      int s = tid;
      int key = s >> 3, c = (s & 7) ^ (key & 7);
      GLOAD16(K + (size_t)((kt + 1) * 64 + key) * 64 + c * 8, Ks[nxt] + s * 8);
      GLOAD16(Vt + (size_t)(kt + 1) * 4096 + s * 8, Vs[nxt] + s * 8);
      if ((kt & 1) && w < 2) {
        int r = w * 64 + lane;
        GLOAD16(mrow + (size_t)(q0 + r) * 32 + (kt + 1),
                (bf16*)&Ms[((kt + 1) >> 1) & 1][0] + r * 8);
      }
    }

    // St[kb] = K Q^T  (C-layout: col=q=l15, row=key=quad*4+reg)
    f32x4 st[4] = {};
#pragma unroll
    for (int ks = 0; ks < 2; ++ks)
#pragma unroll
      for (int kb = 0; kb < 4; ++kb) {
        int key = kb * 16 + l15;
        bf16x8 kf = *(const bf16x8*)(Ks[cur] + (key * 8 + ((ks * 4 + quad) ^ (key & 7))) * 8);
        st[kb] = MFMA16(kf, qf[ks], st[kb]);
      }

    // mask + exp2 + pack to PV A-fragments
    const ull* Mcur = Ms[(kt >> 1) & 1];
    const ull word = Mcur[(w * 16 + l15) * 2 + cur];
    s16x4 pf[4];
#pragma unroll
    for (int kb = 0; kb < 4; ++kb) {
      const unsigned nib = (unsigned)(word >> (kb * 16 + quad * 4)) & 0xFu;
      float p0 = (nib & 1u) ? __builtin_amdgcn_exp2f(st[kb][0]) : 0.f;
      float p1 = (nib & 2u) ? __builtin_amdgcn_exp2f(st[kb][1]) : 0.f;
      float p2 = (nib & 4u) ? __builtin_amdgcn_exp2f(st[kb][2]) : 0.f;
      float p3 = (nib & 8u) ? __builtin_amdgcn_exp2f(st[kb][3]) : 0.f;
      bf16x4 pb = {(bf16)p0, (bf16)p1, (bf16)p2, (bf16)p3};
      pf[kb] = __builtin_bit_cast(s16x4, pb);
    }

    // lsum via ones-MFMA (accL rows == accO rows)
#pragma unroll
    for (int kb = 0; kb < 4; ++kb)
      accL = MFMA16K16(pf[kb], onesf, accL);

    // O += P V  (A=P regs [m=q=l15, k=quad*4+j], B=V frag [k=quad*4+j, n=d=db*16+l15])
#pragma unroll
    for (int kb = 0; kb < 4; ++kb)
#pragma unroll
      for (int db = 0; db < 4; ++db) {
        s16x4 vf = *(const s16x4*)(Vs[cur] + ((size_t)((kb * 4 + quad) * 64 + db * 16 + l15)) * 4);
        accO[db] = MFMA16K16(pf[kb], vf, accO[db]);
      }
    __syncthreads();
  }

  // epilogue: accL[r] = lsum for q = w*16+quad*4+r — no shuffles
  float rl[4];
#pragma unroll
  for (int r = 0; r < 4; ++r) rl[r] = 1.0f / accL[r];
#pragma unroll
  for (int db = 0; db < 4; ++db) {
    const int col = h * 64 + db * 16 + l15;
#pragma unroll
    for (int r = 0; r < 4; ++r) {
      const int rowg = q0 + w * 16 + quad * 4 + r;
      ctx[((size_t)b * L_ + rowg) * 1024 + col] = (bf16)(accO[db][r] * rl[r]);
    }
  }
}

extern "C" void kernel_launch(void* const* d_in, const int* in_sizes, int n_in,
                              void* d_out, int out_size, void* d_ws, size_t ws_size,
                              hipStream_t stream) {
  (void)in_sizes; (void)n_in; (void)out_size; (void)ws_size;
  const float* q    = (const float*)d_in[0];
  const float* k    = (const float*)d_in[1];
  const float* v    = (const float*)d_in[2];
  const int*   mask = (const int*)d_in[3];
  const float* Wq = (const float*)d_in[4];
  const float* bq = (const float*)d_in[5];
  const float* Wk = (const float*)d_in[6];
  const float* bk = (const float*)d_in[7];
  const float* Wv = (const float*)d_in[8];
  const float* bv = (const float*)d_in[9];
  const float* Wo = (const float*)d_in[10];
  const float* bo = (const float*)d_in[11];
  float* out = (float*)d_out;

  char* ws = (char*)d_ws;
  const size_t SX = (size_t)4096 * 1024 * 2;  // 8 MB
  const size_t SW = (size_t)1024 * 1024 * 2;  // 2 MB
  bf16* X   = (bf16*)(ws);                    // Xq|Xk|Xv
  bf16* Wt  = (bf16*)(ws + 3 * SX);           // Wqt|Wkt|Wvt|Wot
  bf16* QKV = (bf16*)(ws + 3 * SX + 4 * SW);  // Qp|Kp|Vt(pre-tiled)
  bf16* Qp  = QKV;
  bf16* Kp  = QKV + 4194304;
  bf16* Vtp = QKV + 2 * 4194304;
  bf16* Ctx = (bf16*)(ws + 6 * SX + 4 * SW);
  ull* mbits = (ull*)(ws + 7 * SX + 4 * SW);

  dim3 blk(256);
  k_prep<<<49152, blk, 0, stream>>>(q, k, v, mask, Wq, Wk, Wv, Wo, X, Wt, mbits);

  k_gemm3<<<dim3(8, 32, 3), blk, 0, stream>>>(X, Wt, bq, bk, bv, QKV);

  k_flash<<<dim3(16, NH_, B_), dim3(512), 0, stream>>>(Qp, Kp, Vtp, mbits, Ctx);

  k_gemmo<<<dim3(8, 64), blk, 0, stream>>>(Ctx, Wt + 3 * 1048576, bo, out);
}

// Round 2
// 267.755 us; speedup vs baseline: 1.0287x; 1.0018x over previous
//
#include <hip/hip_runtime.h>
#include <stdint.h>

typedef __bf16 bf16;
typedef __bf16 bf16x8 __attribute__((ext_vector_type(8)));
typedef __bf16 bf16x4 __attribute__((ext_vector_type(4)));
typedef __bf16 bf16x2 __attribute__((ext_vector_type(2)));
typedef float  f32x4  __attribute__((ext_vector_type(4)));
typedef float  f32x16 __attribute__((ext_vector_type(16)));
typedef short  s16x4  __attribute__((ext_vector_type(4)));
typedef short  s16x8  __attribute__((ext_vector_type(8)));
typedef unsigned int u32x2 __attribute__((ext_vector_type(2)));
typedef unsigned int u32x4 __attribute__((ext_vector_type(4)));
typedef unsigned long long ull;

#define GLOAD16(gptr, lptr)                                                     \
  __builtin_amdgcn_global_load_lds(                                             \
      (const __attribute__((address_space(1))) void*)(gptr),                    \
      (__attribute__((address_space(3))) void*)(lptr), 16, 0, 0)

#define MFMA16(a, b, c) __builtin_amdgcn_mfma_f32_16x16x32_bf16((a), (b), (c), 0, 0, 0)
#define MFMA32(a, b, c) __builtin_amdgcn_mfma_f32_32x32x16_bf16((a), (b), (c), 0, 0, 0)

static constexpr int B_ = 2, L_ = 2048, NH_ = 16, DH_ = 64;
static constexpr float QSCALE = 0.18033688011112042f;  // 0.125 * log2(e)

// ---------- fused prep: maskbits | fp32->bf16 cvt | weight transpose ----------
__global__ __launch_bounds__(256) void k_prep(const float* __restrict__ q,
                                              const float* __restrict__ k,
                                              const float* __restrict__ v,
                                              const int* __restrict__ mask,
                                              const float* __restrict__ wq,
                                              const float* __restrict__ wk,
                                              const float* __restrict__ wv,
                                              const float* __restrict__ wo,
                                              bf16* __restrict__ X,
                                              bf16* __restrict__ Wt,
                                              ull* __restrict__ mb) {
  __shared__ float t[32][33];
  const int bid = blockIdx.x, tid = threadIdx.x;
  if (bid < 32768) {  // mask int32 -> packed bits
    int tt = bid * 256 + tid;
    ull bal = __ballot(mask[tt] != 0);
    if ((tid & 63) == 0) mb[tt >> 6] = bal;
  } else if (bid < 45056) {  // fp32 -> bf16 x4
    int u = bid - 32768;
    int z = u >> 12, x = u & 4095;
    const float* in = z == 0 ? q : (z == 1 ? k : v);
    bf16* out = X + (size_t)z * 4194304;
    int i = x * 256 + tid;
    const float4 f = ((const float4*)in)[i];
    bf16x4 o = {(bf16)f.x, (bf16)f.y, (bf16)f.z, (bf16)f.w};
    ((bf16x4*)out)[i] = o;
  } else {  // weight fp32 KxN -> bf16 NxK
    int u = bid - 45056;
    int z = u >> 10, rem = u & 1023;
    const float* in = z == 0 ? wq : (z == 1 ? wk : (z == 2 ? wv : wo));
    bf16* out = Wt + (size_t)z * 1048576;
    int bx = (rem & 31) * 32, by = (rem >> 5) * 32;
    int x = tid & 31, y = tid >> 5;
#pragma unroll
    for (int r = 0; r < 4; ++r)
      t[y + r * 8][x] = in[(size_t)(by + y + r * 8) * 1024 + bx + x];
    __syncthreads();
#pragma unroll
    for (int r = 0; r < 4; ++r)
      out[(size_t)(bx + y + r * 8) * 1024 + by + x] = (bf16)t[x][y + r * 8];
  }
}

// ---------- batched 3-proj GEMM: 128x128 tile, BK=32 ----------
// z=0: Q scaled by QSCALE. z=2: V pre-tiled per raw-view head (faithful-bug reshape):
//   h = l>>7, i = (l&127)*16 + (col>>6), d = col&63; Vt[bh][((i>>2)*64 + d)*4 + (i&3)]
__global__ __launch_bounds__(256) void k_gemm3(const bf16* __restrict__ Xb,
                                               const bf16* __restrict__ Wb,
                                               const float* __restrict__ b0,
                                               const float* __restrict__ b1,
                                               const float* __restrict__ b2,
                                               bf16* __restrict__ Ob) {
  const int z = blockIdx.z;
  const bf16* A  = Xb + (size_t)z * 4194304;
  const bf16* Bt = Wb + (size_t)z * 1048576;
  const float* bias = z == 0 ? b0 : (z == 1 ? b1 : b2);
  bf16* C = Ob + (size_t)z * 4194304;
  const int m0 = blockIdx.y * 128, n0 = blockIdx.x * 128;
  __shared__ __align__(16) bf16 As[128 * 32];  // slot(r,c) = r*4 + (c ^ ((r>>1)&3))
  __shared__ __align__(16) bf16 Bs[128 * 32];
  const int tid = threadIdx.x, lane = tid & 63, w = tid >> 6, quad = lane >> 4, l15 = lane & 15;
  const int wm = (w & 1) * 64, wn = (w >> 1) * 64;
  f32x4 acc[4][4] = {};
  for (int kt = 0; kt < 32; ++kt) {
    const int kk = kt * 32;
#pragma unroll
    for (int i = 0; i < 2; ++i) {
      int s = tid + i * 256;
      int r = s >> 2, c = (s & 3) ^ ((r >> 1) & 3);
      GLOAD16(A + (size_t)(m0 + r) * 1024 + kk + c * 8, As + s * 8);
      GLOAD16(Bt + (size_t)(n0 + r) * 1024 + kk + c * 8, Bs + s * 8);
    }
    __syncthreads();
    bf16x8 af[4], bb[4];
#pragma unroll
    for (int i = 0; i < 4; ++i) {
      int ra = wm + i * 16 + l15, rb = wn + i * 16 + l15;
      af[i] = *(const bf16x8*)(As + (ra * 4 + (quad ^ ((ra >> 1) & 3))) * 8);
      bb[i] = *(const bf16x8*)(Bs + (rb * 4 + (quad ^ ((rb >> 1) & 3))) * 8);
    }
#pragma unroll
    for (int mi = 0; mi < 4; ++mi)
#pragma unroll
      for (int ni = 0; ni < 4; ++ni)
        acc[mi][ni] = MFMA16(af[mi], bb[ni], acc[mi][ni]);
    __syncthreads();
  }
  const float scale = (z == 0) ? QSCALE : 1.0f;
#pragma unroll
  for (int mi = 0; mi < 4; ++mi)
#pragma unroll
    for (int ni = 0; ni < 4; ++ni) {
      int row = m0 + wm + mi * 16 + quad * 4;
      int col = n0 + wn + ni * 16 + l15;
      float bz = bias[col];
      if (z == 2) {
        int b_ = row >> 11, l = row & 2047;
        int hh = l >> 7;
        int i0 = (l & 127) * 16 + (col >> 6);
        int d  = col & 63;
        bf16* dst = C + (size_t)(b_ * 16 + hh) * 131072;
#pragma unroll
        for (int r = 0; r < 4; ++r) {
          int iK = i0 + 16 * r;
          dst[((size_t)(iK >> 2) * 64 + d) * 4 + (iK & 3)] = (bf16)(acc[mi][ni][r] + bz);
        }
      } else {
#pragma unroll
        for (int r = 0; r < 4; ++r)
          C[(size_t)(row + r) * 1024 + col] = (bf16)((acc[mi][ni][r] + bz) * scale);
      }
    }
}

// ---------- output GEMM: 64x128 tile, fp32 out + bias ----------
__global__ __launch_bounds__(256) void k_gemmo(const bf16* __restrict__ A,
                                               const bf16* __restrict__ Bt,
                                               const float* __restrict__ bias,
                                               float* __restrict__ C) {
  const int m0 = blockIdx.y * 64, n0 = blockIdx.x * 128;
  __shared__ __align__(16) bf16 As[64 * 32];
  __shared__ __align__(16) bf16 Bs[128 * 32];
  const int tid = threadIdx.x, lane = tid & 63, w = tid >> 6, quad = lane >> 4, l15 = lane & 15;
  const int wn = w * 32;
  f32x4 acc[4][2] = {};
  for (int kt = 0; kt < 32; ++kt) {
    const int kk = kt * 32;
    {
      int r = tid >> 2, c = (tid & 3) ^ ((r >> 1) & 3);
      GLOAD16(A + (size_t)(m0 + r) * 1024 + kk + c * 8, As + tid * 8);
    }
#pragma unroll
    for (int i = 0; i < 2; ++i) {
      int s = tid + i * 256;
      int r = s >> 2, c = (s & 3) ^ ((r >> 1) & 3);
      GLOAD16(Bt + (size_t)(n0 + r) * 1024 + kk + c * 8, Bs + s * 8);
    }
    __syncthreads();
    bf16x8 af[4], bb[2];
#pragma unroll
    for (int i = 0; i < 4; ++i) {
      int ra = i * 16 + l15;
      af[i] = *(const bf16x8*)(As + (ra * 4 + (quad ^ ((ra >> 1) & 3))) * 8);
    }
#pragma unroll
    for (int i = 0; i < 2; ++i) {
      int rb = wn + i * 16 + l15;
      bb[i] = *(const bf16x8*)(Bs + (rb * 4 + (quad ^ ((rb >> 1) & 3))) * 8);
    }
#pragma unroll
    for (int mi = 0; mi < 4; ++mi)
#pragma unroll
      for (int ni = 0; ni < 2; ++ni)
        acc[mi][ni] = MFMA16(af[mi], bb[ni], acc[mi][ni]);
    __syncthreads();
  }
#pragma unroll
  for (int mi = 0; mi < 4; ++mi)
#pragma unroll
    for (int ni = 0; ni < 2; ++ni) {
      int row = m0 + mi * 16 + quad * 4;
      int col = n0 + wn + ni * 16 + l15;
      float bz = bias[col];
#pragma unroll
      for (int r = 0; r < 4; ++r)
        C[(size_t)(row + r) * 1024 + col] = acc[mi][ni][r] + bz;
    }
}

static __device__ __forceinline__ unsigned pack2(float a, float b) {
  bf16x2 t = {(bf16)a, (bf16)b};
  return __builtin_bit_cast(unsigned, t);
}

// ---------- flash attention, 32x32x16 MFMA restructure ----------
// q-tile 128, 512 threads = 8 waves = (key-half kh x q-quarter qq).
// Each wave: 32q x 32k score block per kt via mfma_f32_32x32x16_bf16:
//   QK^T 4 MFMA + lsum 2 + PV 4  (vs 8 K32 + 20 half-rate K16 before).
// P->A-frag repack: cvt_pk pairs + permlane32_swap (HK T12 pattern).
// Per-wave LDS reads halve (each wave touches only its 32-key half of K/V).
// Epilogue: cross-wave (kh) combine of O/lsum partials through reused LDS.
__global__ __launch_bounds__(512, 4) void k_flash(const bf16* __restrict__ Qp,
                                                  const bf16* __restrict__ Kp,
                                                  const bf16* __restrict__ Vtp,
                                                  const ull* __restrict__ mb,
                                                  bf16* __restrict__ ctx) {
  const int b = blockIdx.z, h = blockIdx.y, q0 = blockIdx.x * 128;
  const size_t HEAD = 131072;
  const bf16* Q  = Qp  + ((size_t)b * NH_ + h) * HEAD;  // pre-scaled by QSCALE
  const bf16* K  = Kp  + ((size_t)b * NH_ + h) * HEAD;  // row-major [key][d]
  const bf16* Vt = Vtp + ((size_t)b * NH_ + h) * HEAD;  // pre-tiled [key>>2][d][key&3]
  const ull* mrow = mb + (size_t)b * L_ * 32;

  // LDS: Ks[2][4096] | Vs[2][4096] | Ms[2][256] = 36864 B (same as R1)
  __shared__ __align__(16) unsigned char RAW[36864];
  bf16* Ksb = (bf16*)RAW;             // swizzled: slot(key,cc), cc = c ^ (key&7)
  bf16* Vsb = (bf16*)(RAW + 16384);   // straight copy of pre-tiled chunk
  ull*  Msb = (ull*)(RAW + 32768);    // [buf][row*2 + parity]

  const int tid = threadIdx.x, lane = tid & 63, w = tid >> 6;
  const int hi = lane >> 5, l31 = lane & 31;
  const int kh = w & 1, qq = w >> 1;

  // Q frags (B-operand: col=q=l31, k=d=ks*16+hi*8+j) straight from global
  bf16x8 qf[4];
#pragma unroll
  for (int ks = 0; ks < 4; ++ks)
    qf[ks] = *(const bf16x8*)(Q + (size_t)(q0 + qq * 32 + l31) * 64 + ks * 16 + hi * 8);

  // initial staging: kt=0 K/V (512 threads x 1 slot), mask word pair (0,1)
  {
    int s = tid;
    int key = s >> 3, c = (s & 7) ^ (key & 7);
    GLOAD16(K + (size_t)key * 64 + c * 8, Ksb + s * 8);
    GLOAD16(Vt + (size_t)s * 8, Vsb + s * 8);
  }
  if (w < 2) {
    int r = w * 64 + lane;
    GLOAD16(mrow + (size_t)(q0 + r) * 32, (bf16*)Msb + r * 8);
  }
  __syncthreads();

  f32x16 accO0 = {}, accO1 = {}, accL = {};
  const s16x8 one8s = {0x3F80, 0x3F80, 0x3F80, 0x3F80, 0x3F80, 0x3F80, 0x3F80, 0x3F80};
  const bf16x8 ones8 = __builtin_bit_cast(bf16x8, one8s);

  for (int kt = 0; kt < 32; ++kt) {
    const int cur = kt & 1;
    const bf16* Kc = Ksb + cur * 4096;
    const bf16* Vc = Vsb + cur * 4096;
    // prefetch next K/V (+mask every other kt) into the other LDS buffer
    if (kt + 1 < 32) {
      const int nxt = cur ^ 1;
      int s = tid;
      int key = s >> 3, c = (s & 7) ^ (key & 7);
      GLOAD16(K + (size_t)((kt + 1) * 64 + key) * 64 + c * 8, Ksb + nxt * 4096 + s * 8);
      GLOAD16(Vt + (size_t)(kt + 1) * 4096 + s * 8, Vsb + nxt * 4096 + s * 8);
      if ((kt & 1) && w < 2) {
        int r = w * 64 + lane;
        GLOAD16(mrow + (size_t)(q0 + r) * 32 + (kt + 1),
                (bf16*)Msb + (((kt + 1) >> 1) & 1) * 1024 + r * 8);
      }
    }

    // St = K Q^T (C: col=q=l31, row=key_rel=(reg&3)+8*(reg>>2)+4*hi)
    f32x16 st = {};
    const int key = kh * 32 + l31;
#pragma unroll
    for (int ks = 0; ks < 4; ++ks) {
      bf16x8 kf = *(const bf16x8*)(Kc + (key * 8 + ((ks * 2 + hi) ^ (key & 7))) * 8);
      st = MFMA32(kf, qf[ks], st);
    }

    // mask + exp2 (in place over st)
    const ull word = Msb[((kt >> 1) & 1) * 256 + (qq * 32 + l31) * 2 + cur];
    const unsigned w32 = (unsigned)(word >> (kh * 32 + 4 * hi));
#pragma unroll
    for (int r = 0; r < 16; ++r) {
      const int bit = (r >> 2) * 8 + (r & 3);
      st[r] = (w32 >> bit) & 1u ? __builtin_amdgcn_exp2f(st[r]) : 0.f;
    }

    // pack P pairs + permlane32_swap -> PV A-frags (k = hi*8 + j)
    bf16x8 af[2];
#pragma unroll
    for (int ks2 = 0; ks2 < 2; ++ks2) {
      const int bb = ks2 * 8;
      unsigned c0 = pack2(st[bb + 0], st[bb + 1]);
      unsigned c1 = pack2(st[bb + 2], st[bb + 3]);
      unsigned c2 = pack2(st[bb + 4], st[bb + 5]);
      unsigned c3 = pack2(st[bb + 6], st[bb + 7]);
      u32x2 s0 = __builtin_amdgcn_permlane32_swap(c0, c2, false, false);
      u32x2 s1 = __builtin_amdgcn_permlane32_swap(c1, c3, false, false);
      u32x4 a4 = {s0.x, s1.x, s0.y, s1.y};
      af[ks2] = __builtin_bit_cast(bf16x8, a4);
    }

    // lsum via ones-MFMA (accL rows == accO rows)
    accL = MFMA32(af[0], ones8, accL);
    accL = MFMA32(af[1], ones8, accL);

    // O += P V  (B-frag: k=hi*8+j, n=d=dblk*32+l31; from pre-tiled Vs)
#pragma unroll
    for (int ks2 = 0; ks2 < 2; ++ks2) {
      const int vb = ((kh * 32 + ks2 * 16 + hi * 8) >> 2) * 64 + l31;  // s16x4 units
      s16x4 a0 = *(const s16x4*)(Vc + (size_t)vb * 4);
      s16x4 a1 = *(const s16x4*)(Vc + (size_t)(vb + 64) * 4);
      s16x4 b0 = *(const s16x4*)(Vc + (size_t)(vb + 32) * 4);
      s16x4 b1 = *(const s16x4*)(Vc + (size_t)(vb + 96) * 4);
      bf16x8 v0 = __builtin_bit_cast(bf16x8, __builtin_shufflevector(a0, a1, 0, 1, 2, 3, 4, 5, 6, 7));
      bf16x8 v1 = __builtin_bit_cast(bf16x8, __builtin_shufflevector(b0, b1, 0, 1, 2, 3, 4, 5, 6, 7));
      accO0 = MFMA32(af[ks2], v0, accO0);
      accO1 = MFMA32(af[ks2], v1, accO1);
    }
    __syncthreads();
  }

  // epilogue: combine kh halves through reused LDS, then normalize + store
  float* red  = (float*)RAW;            // [qq][32 q][64 d] = 32 KB
  float* redL = (float*)(RAW + 32768);  // [qq][32 q] = 512 B
  if (kh == 1) {
#pragma unroll
    for (int r = 0; r < 16; ++r) {
      const int qrel = (r & 3) + 8 * (r >> 2) + 4 * hi;
      red[qq * 2048 + qrel * 64 + l31]      = accO0[r];
      red[qq * 2048 + qrel * 64 + 32 + l31] = accO1[r];
      if (l31 == 0) redL[qq * 32 + qrel] = accL[r];
    }
  }
  __syncthreads();
  if (kh == 0) {
#pragma unroll
    for (int r = 0; r < 16; ++r) {
      const int qrel = (r & 3) + 8 * (r >> 2) + 4 * hi;
      const float ls = accL[r] + redL[qq * 32 + qrel];
      const float rl = 1.0f / ls;
      const float o0 = accO0[r] + red[qq * 2048 + qrel * 64 + l31];
      const float o1 = accO1[r] + red[qq * 2048 + qrel * 64 + 32 + l31];
      const int rowg = q0 + qq * 32 + qrel;
      ctx[((size_t)b * L_ + rowg) * 1024 + h * 64 + l31]      = (bf16)(o0 * rl);
      ctx[((size_t)b * L_ + rowg) * 1024 + h * 64 + 32 + l31] = (bf16)(o1 * rl);
    }
  }
}

extern "C" void kernel_launch(void* const* d_in, const int* in_sizes, int n_in,
                              void* d_out, int out_size, void* d_ws, size_t ws_size,
                              hipStream_t stream) {
  (void)in_sizes; (void)n_in; (void)out_size; (void)ws_size;
  const float* q    = (const float*)d_in[0];
  const float* k    = (const float*)d_in[1];
  const float* v    = (const float*)d_in[2];
  const int*   mask = (const int*)d_in[3];
  const float* Wq = (const float*)d_in[4];
  const float* bq = (const float*)d_in[5];
  const float* Wk = (const float*)d_in[6];
  const float* bk = (const float*)d_in[7];
  const float* Wv = (const float*)d_in[8];
  const float* bv = (const float*)d_in[9];
  const float* Wo = (const float*)d_in[10];
  const float* bo = (const float*)d_in[11];
  float* out = (float*)d_out;

  char* ws = (char*)d_ws;
  const size_t SX = (size_t)4096 * 1024 * 2;  // 8 MB
  const size_t SW = (size_t)1024 * 1024 * 2;  // 2 MB
  bf16* X   = (bf16*)(ws);                    // Xq|Xk|Xv
  bf16* Wt  = (bf16*)(ws + 3 * SX);           // Wqt|Wkt|Wvt|Wot
  bf16* QKV = (bf16*)(ws + 3 * SX + 4 * SW);  // Qp|Kp|Vt(pre-tiled)
  bf16* Qp  = QKV;
  bf16* Kp  = QKV + 4194304;
  bf16* Vtp = QKV + 2 * 4194304;
  bf16* Ctx = (bf16*)(ws + 6 * SX + 4 * SW);
  ull* mbits = (ull*)(ws + 7 * SX + 4 * SW);

  dim3 blk(256);
  k_prep<<<49152, blk, 0, stream>>>(q, k, v, mask, Wq, Wk, Wv, Wo, X, Wt, mbits);

  k_gemm3<<<dim3(8, 32, 3), blk, 0, stream>>>(X, Wt, bq, bk, bv, QKV);

  k_flash<<<dim3(16, NH_, B_), dim3(512), 0, stream>>>(Qp, Kp, Vtp, mbits, Ctx);

  k_gemmo<<<dim3(8, 64), blk, 0, stream>>>(Ctx, Wt + 3 * 1048576, bo, out);
}